// Round 3
// baseline (72.930 us; speedup 1.0000x reference)
//
#include <hip/hip_runtime.h>

// Dims fixed by reference setup_inputs
#define CIN  128
#define CS   32
#define CHUNKF 32768       // HW*T floats per (n, channel)
#define PPOS 8             // hw positions per fused block
// ws float layout:
// [0,4096)      qw1   [32][128]
// [4096,8192)   qw2   [128][32]
// [8192,8320)   msum  [128]
// [8320,8448)   kappa [128]
// [8448,12544)  qw1T  [128][32]   qw1T[c*32+o] = qw1[o][c]
// [12544,16640) qw2T  [32][128]   qw2T[j*128+o] = qw2[o][j]

__global__ __launch_bounds__(128) void wnorm_kernel(
    const float* __restrict__ v1, const float* __restrict__ g1,
    const float* __restrict__ v2, const float* __restrict__ g2,
    float* __restrict__ ws) {
  int b = blockIdx.x, tid = threadIdx.x;
  bool first = (b < 32);
  int row = first ? b : b - 32;
  int len = first ? 128 : 32;
  const float* v = first ? v1 : v2;
  const float* g = first ? g1 : g2;

  double val = 0.0;
  if (tid < len) { double t = (double)v[row * len + tid]; val = t * t; }
  for (int off = 32; off >= 1; off >>= 1) val += __shfl_down(val, off);
  __shared__ double partial[2];
  if ((tid & 63) == 0) partial[tid >> 6] = val;
  __syncthreads();
  double norm = sqrt(partial[0] + partial[1]);
  if (tid < len) {
    double w = (double)g[row] * (double)v[row * len + tid] / norm;
    double qd = rint(w * 32.0) * 0.03125;           // step = 2/64
    qd = fmin(fmax(qd, -2.0), 1.984375);
    float qf = (float)qd;
    if (first) {                                    // row=o1, tid=c
      ws[row * 128 + tid]        = qf;              // qw1
      ws[8448 + tid * 32 + row]  = qf;              // qw1T
    } else {                                        // row=o2, tid=j
      ws[4096 + row * 32 + tid]  = qf;              // qw2
      ws[12544 + tid * 128 + row] = qf;             // qw2T
    }
  }
}

// msum[i] += sum over chunk of (T - t) * x   (scaled later by 1/(N*HW*T))
__global__ __launch_bounds__(256) void mean_kernel(
    const float* __restrict__ x, float* __restrict__ msum) {
  int b = blockIdx.x, tid = threadIdx.x;
  int chunk = b >> 2, quarter = b & 3;      // chunk = n*128 + i
  int i = chunk & 127;
  const float4* xp = (const float4*)(x + (size_t)chunk * CHUNKF + (size_t)quarter * 8192);
  float acc = 0.f;
#pragma unroll
  for (int it = 0; it < 8; ++it) {
    int f4i = tid + 256 * it;
    float4 v = xp[f4i];
    int t0 = (4 * f4i) & 31;
    acc += v.x * (float)(32 - t0) + v.y * (float)(31 - t0)
         + v.z * (float)(30 - t0) + v.w * (float)(29 - t0);
  }
  for (int off = 32; off >= 1; off >>= 1) acc += __shfl_down(acc, off);
  __shared__ float part[4];
  if ((tid & 63) == 0) part[tid >> 6] = acc;
  __syncthreads();
  if (tid == 0) atomicAdd(&msum[i], part[0] + part[1] + part[2] + part[3]);
}

// kappa[o2] = sum_j qw2[o2][j] * (sum_c qw1[j][c] * mbar[c])
__global__ __launch_bounds__(128) void kappa_kernel(float* __restrict__ ws) {
  __shared__ float z[32];
  int tid = threadIdx.x;
  const float* qw1 = ws;
  const float* qw2 = ws + 4096;
  const float* msum = ws + 8192;
  if (tid < 32) {
    float acc = 0.f;
    for (int c = 0; c < 128; ++c) acc += qw1[tid * 128 + c] * msum[c];
    z[tid] = acc * (1.0f / 131072.0f);
  }
  __syncthreads();
  float k = 0.f;
  for (int j = 0; j < 32; ++j) k += qw2[tid * 32 + j] * z[j];
  ws[8320 + tid] = k;
}

// Fused: u[t] = (qw2*qw1*x)[t] via two register-tiled GEMMs; epilogue
// S = cumsum_t u, a = clip(S - kappa), out = diff_t a.
__global__ __launch_bounds__(256, 3) void fused_kernel(
    const float* __restrict__ x, const float* __restrict__ ws,
    float* __restrict__ out) {
  const float* qw1T = ws + 8448;    // [c][32]
  const float* qw2T = ws + 12544;   // [j][128]
  const float* kap  = ws + 8320;    // [128]

  __shared__ __align__(16) float st[2][64][32];   // x stage: row = c'*8+p, swizzled cols
  __shared__ __align__(16) float z1[256][32];     // row = o1*8+p, swizzled cols

  const int tid = threadIdx.x;
  const int og = tid >> 5;          // 0..7
  const int p  = (tid >> 2) & 7;    // 0..7
  const int q  = tid & 3;           // 0..3 (t-run 8q..8q+7)
  // XOR-swizzled float4 column offsets (all rows this thread touches are ≡ p mod 8)
  const int c0 = ((2 * q)     ^ p) * 4;
  const int c1 = ((2 * q + 1) ^ p) * 4;

  const int n   = blockIdx.x >> 7;
  const int hw0 = (blockIdx.x & 127) * PPOS;
  const float* xbase = x + (size_t)n * CIN * CHUNKF + (size_t)(hw0 + p) * 32 + q * 8;
  float* outbase = out + (size_t)n * CIN * CHUNKF + (size_t)(hw0 + p) * 32 + q * 8;

  // ---- prolog: load x(ch=0) + w1(ch=0), stage st[0]
  float4 xn0, xn1, wc[8], wn[8];
  {
    const float* xp = xbase + (size_t)og * CHUNKF;
    xn0 = ((const float4*)xp)[0];
    xn1 = ((const float4*)xp)[1];
    const float* wp = qw1T + og * 4;
#pragma unroll
    for (int cl = 0; cl < 8; ++cl) wc[cl] = *(const float4*)(wp + cl * 32);
  }
  *(float4*)&st[0][og * 8 + p][c0] = xn0;
  *(float4*)&st[0][og * 8 + p][c1] = xn1;

  float acc1[4][8];
#pragma unroll
  for (int o = 0; o < 4; ++o)
#pragma unroll
    for (int t = 0; t < 8; ++t) acc1[o][t] = 0.f;

  // ---- stage 1: acc1[o][t] = sum_c qw1T[c][og*4+o] * x[c][t], double-buffered
  for (int ch = 0; ch < 16; ++ch) {
    if (ch < 15) {
      const float* xp = xbase + (size_t)((ch + 1) * 8 + og) * CHUNKF;
      xn0 = ((const float4*)xp)[0];
      xn1 = ((const float4*)xp)[1];
      const float* wp = qw1T + ((ch + 1) * 8) * 32 + og * 4;
#pragma unroll
      for (int cl = 0; cl < 8; ++cl) wn[cl] = *(const float4*)(wp + cl * 32);
    }
    __syncthreads();                       // st[ch&1] fully staged
#pragma unroll
    for (int cl = 0; cl < 8; ++cl) {
      const float* sr = &st[ch & 1][cl * 8 + p][0];
      float4 sA = *(const float4*)(sr + c0);
      float4 sB = *(const float4*)(sr + c1);
      float sv[8] = {sA.x, sA.y, sA.z, sA.w, sB.x, sB.y, sB.z, sB.w};
      float wv[4] = {wc[cl].x, wc[cl].y, wc[cl].z, wc[cl].w};
#pragma unroll
      for (int o = 0; o < 4; ++o)
#pragma unroll
        for (int t = 0; t < 8; ++t) acc1[o][t] += wv[o] * sv[t];
    }
    if (ch < 15) {
      *(float4*)&st[(ch + 1) & 1][og * 8 + p][c0] = xn0;
      *(float4*)&st[(ch + 1) & 1][og * 8 + p][c1] = xn1;
#pragma unroll
      for (int cl = 0; cl < 8; ++cl) wc[cl] = wn[cl];
    }
  }

  // ---- z1 writeout
#pragma unroll
  for (int o = 0; o < 4; ++o) {
    float* zr = &z1[(og * 4 + o) * 8 + p][0];
    *(float4*)(zr + c0) = make_float4(acc1[o][0], acc1[o][1], acc1[o][2], acc1[o][3]);
    *(float4*)(zr + c1) = make_float4(acc1[o][4], acc1[o][5], acc1[o][6], acc1[o][7]);
  }
  __syncthreads();

  // ---- stage 2 + epilogue, two halves of 8 out-channels each
#pragma unroll 1
  for (int h = 0; h < 2; ++h) {
    float a2[8][8];
#pragma unroll
    for (int k = 0; k < 8; ++k)
#pragma unroll
      for (int t = 0; t < 8; ++t) a2[k][t] = 0.f;
    const float* w2p = qw2T + h * 64 + og * 8;
#pragma unroll 2
    for (int j = 0; j < 32; ++j) {
      float4 wA = *(const float4*)(w2p + j * 128);
      float4 wB = *(const float4*)(w2p + j * 128 + 4);
      const float* zr = &z1[j * 8 + p][0];
      float4 zA = *(const float4*)(zr + c0);
      float4 zB = *(const float4*)(zr + c1);
      float zv[8] = {zA.x, zA.y, zA.z, zA.w, zB.x, zB.y, zB.z, zB.w};
      float wv[8] = {wA.x, wA.y, wA.z, wA.w, wB.x, wB.y, wB.z, wB.w};
#pragma unroll
      for (int k = 0; k < 8; ++k)
#pragma unroll
        for (int t = 0; t < 8; ++t) a2[k][t] += wv[k] * zv[t];
    }
    float4 kA = *(const float4*)(kap + h * 64 + og * 8);
    float4 kB = *(const float4*)(kap + h * 64 + og * 8 + 4);
    float kv[8] = {kA.x, kA.y, kA.z, kA.w, kB.x, kB.y, kB.z, kB.w};
#pragma unroll
    for (int k = 0; k < 8; ++k) {
      float run = 0.f, S[8];
#pragma unroll
      for (int t = 0; t < 8; ++t) { run += a2[k][t]; S[t] = run; }
      float r1 = __shfl_up(run, 1);
      float r2 = __shfl_up(run, 2);
      float r3 = __shfl_up(run, 3);
      float pre = (q > 0 ? r1 : 0.f) + (q > 1 ? r2 : 0.f) + (q > 2 ? r3 : 0.f);
      float kpp = kv[k];
      float prev = (q == 0) ? 0.f : fminf(fmaxf(pre - kpp, -6.f), 6.f);
      float d[8];
#pragma unroll
      for (int t = 0; t < 8; ++t) {
        float a = fminf(fmaxf(pre + S[t] - kpp, -6.f), 6.f);
        d[t] = a - prev; prev = a;
      }
      float* op = outbase + (size_t)(h * 64 + og * 8 + k) * CHUNKF;
      ((float4*)op)[0] = make_float4(d[0], d[1], d[2], d[3]);
      ((float4*)op)[1] = make_float4(d[4], d[5], d[6], d[7]);
    }
  }
}

extern "C" void kernel_launch(void* const* d_in, const int* in_sizes, int n_in,
                              void* d_out, int out_size, void* d_ws, size_t ws_size,
                              hipStream_t stream) {
  const float* x  = (const float*)d_in[0];
  const float* v1 = (const float*)d_in[1];
  const float* g1 = (const float*)d_in[2];
  const float* v2 = (const float*)d_in[3];
  const float* g2 = (const float*)d_in[4];
  float* ws  = (float*)d_ws;
  float* out = (float*)d_out;

  hipMemsetAsync(ws + 8192, 0, 128 * sizeof(float), stream);
  wnorm_kernel<<<160, 128, 0, stream>>>(v1, g1, v2, g2, ws);
  mean_kernel<<<2048, 256, 0, stream>>>(x, ws + 8192);
  kappa_kernel<<<1, 128, 0, stream>>>(ws);
  fused_kernel<<<512, 256, 0, stream>>>(x, ws, out);
}

// Round 4
// 68.485 us; speedup vs baseline: 1.0649x; 1.0649x over previous
//
#include <hip/hip_runtime.h>

// Dims fixed by reference setup_inputs
#define CIN  128
#define CS   32
#define CHUNKF 32768       // HW*T floats per (n, channel)
#define PPOS 4             // hw positions per fused block
// ws float layout:
// [0,4096)      qw1   [32][128]
// [4096,8192)   qw2   [128][32]
// [8192,8320)   msum  [128]
// [8320,8448)   kappa [128]
// [8448,12544)  qw1T  [128][32]   qw1T[c*32+o] = qw1[o][c]
// [12544,16640) qw2T  [32][128]   qw2T[j*128+o] = qw2[o][j]

__global__ __launch_bounds__(128) void wnorm_kernel(
    const float* __restrict__ v1, const float* __restrict__ g1,
    const float* __restrict__ v2, const float* __restrict__ g2,
    float* __restrict__ ws) {
  int b = blockIdx.x, tid = threadIdx.x;
  bool first = (b < 32);
  int row = first ? b : b - 32;
  int len = first ? 128 : 32;
  const float* v = first ? v1 : v2;
  const float* g = first ? g1 : g2;

  double val = 0.0;
  if (tid < len) { double t = (double)v[row * len + tid]; val = t * t; }
  for (int off = 32; off >= 1; off >>= 1) val += __shfl_down(val, off);
  __shared__ double partial[2];
  if ((tid & 63) == 0) partial[tid >> 6] = val;
  __syncthreads();
  double norm = sqrt(partial[0] + partial[1]);
  if (tid < len) {
    double w = (double)g[row] * (double)v[row * len + tid] / norm;
    double qd = rint(w * 32.0) * 0.03125;           // step = 2/64
    qd = fmin(fmax(qd, -2.0), 1.984375);
    float qf = (float)qd;
    if (first) {                                    // row=o1, tid=c
      ws[row * 128 + tid]        = qf;              // qw1
      ws[8448 + tid * 32 + row]  = qf;              // qw1T
    } else {                                        // row=o2, tid=j
      ws[4096 + row * 32 + tid]  = qf;              // qw2
      ws[12544 + tid * 128 + row] = qf;             // qw2T
    }
  }
}

// msum[i] += sum over chunk of (T - t) * x   (scaled later by 1/(N*HW*T))
__global__ __launch_bounds__(256) void mean_kernel(
    const float* __restrict__ x, float* __restrict__ msum) {
  int b = blockIdx.x, tid = threadIdx.x;
  int chunk = b >> 2, quarter = b & 3;      // chunk = n*128 + i
  int i = chunk & 127;
  const float4* xp = (const float4*)(x + (size_t)chunk * CHUNKF + (size_t)quarter * 8192);
  float acc = 0.f;
#pragma unroll
  for (int it = 0; it < 8; ++it) {
    int f4i = tid + 256 * it;
    float4 v = xp[f4i];
    int t0 = (4 * f4i) & 31;
    acc += v.x * (float)(32 - t0) + v.y * (float)(31 - t0)
         + v.z * (float)(30 - t0) + v.w * (float)(29 - t0);
  }
  for (int off = 32; off >= 1; off >>= 1) acc += __shfl_down(acc, off);
  __shared__ float part[4];
  if ((tid & 63) == 0) part[tid >> 6] = acc;
  __syncthreads();
  if (tid == 0) atomicAdd(&msum[i], part[0] + part[1] + part[2] + part[3]);
}

// kappa[o2] = sum_j qw2[o2][j] * (sum_c qw1[j][c] * mbar[c])
__global__ __launch_bounds__(128) void kappa_kernel(float* __restrict__ ws) {
  __shared__ float z[32];
  int tid = threadIdx.x;
  const float* qw1 = ws;
  const float* qw2 = ws + 4096;
  const float* msum = ws + 8192;
  if (tid < 32) {
    float acc = 0.f;
    for (int c = 0; c < 128; ++c) acc += qw1[tid * 128 + c] * msum[c];
    z[tid] = acc * (1.0f / 131072.0f);
  }
  __syncthreads();
  float k = 0.f;
  for (int j = 0; j < 32; ++j) k += qw2[tid * 32 + j] * z[j];
  ws[8320 + tid] = k;
}

// Fused: u = qw2*(qw1*x) via two register-tiled GEMMs; epilogue
// S = cumsum_t u, a = clip(S - kappa), out = diff_t a.
// Thread map: tid = og*32 + p*8 + u  (og:0..7 channel/output group,
// p:0..3 hw position, u:0..7 t-quad -> t = 4u..4u+3).
// All LDS rows are 512B per channel-slot: byte = slot*512 + p*128 + u*16;
// each half-wave covers 32 consecutive 16B chunks -> conflict-free.
__global__ __launch_bounds__(256, 4) void fused_kernel(
    const float* __restrict__ x, const float* __restrict__ ws,
    float* __restrict__ out) {
  const float* qw1T = ws + 8448;    // [c][32]
  const float* qw2T = ws + 12544;   // [j][128]
  const float* kap  = ws + 8320;    // [128]

  __shared__ __align__(16) float w1s[4096];      // 16 KB: qw1T copy [c*32+o]
  __shared__ __align__(16) float z1s[4096];      // 16 KB: z [j][p][t] = j*128+p*32+t
  __shared__ __align__(16) float st[2][1024];    //  8 KB: x stage [cl][p][t]

  const int tid = threadIdx.x;
  const int og = tid >> 5;          // 0..7
  const int p  = (tid >> 3) & 3;    // 0..3
  const int u  = tid & 7;           // 0..7 ; t = 4u..4u+3

  // preload qw1T into LDS (covered by first __syncthreads)
#pragma unroll
  for (int k = 0; k < 16; ++k) w1s[k * 256 + tid] = qw1T[k * 256 + tid];

  const int n   = blockIdx.x >> 8;
  const int hw0 = (blockIdx.x & 255) * PPOS;
  const int coloff = (hw0 + p) * 32 + u * 4;
  const float* xbase = x + (size_t)n * CIN * CHUNKF + coloff;

  // prolog: stage chunk 0
  float4 xn = *(const float4*)(xbase + (size_t)og * CHUNKF);
  *(float4*)&st[0][og * 128 + p * 32 + u * 4] = xn;

  float a1[4][4];
#pragma unroll
  for (int o = 0; o < 4; ++o)
#pragma unroll
    for (int k = 0; k < 4; ++k) a1[o][k] = 0.f;

  // ---- stage 1: a1[o][k] = sum_c qw1T[c][og*4+o] * x[c][t4u+k]
  for (int ch = 0; ch < 16; ++ch) {
    if (ch < 15)
      xn = *(const float4*)(xbase + (size_t)((ch + 1) * 8 + og) * CHUNKF);
    __syncthreads();                     // st[ch&1] staged; prev buffer free
#pragma unroll
    for (int cl = 0; cl < 8; ++cl) {
      float4 wv = *(const float4*)&w1s[(ch * 8 + cl) * 32 + og * 4];
      float4 sv = *(const float4*)&st[ch & 1][cl * 128 + p * 32 + u * 4];
      float w[4] = {wv.x, wv.y, wv.z, wv.w};
      float s[4] = {sv.x, sv.y, sv.z, sv.w};
#pragma unroll
      for (int o = 0; o < 4; ++o)
#pragma unroll
        for (int k = 0; k < 4; ++k) a1[o][k] += w[o] * s[k];
    }
    if (ch < 15)
      *(float4*)&st[(ch + 1) & 1][og * 128 + p * 32 + u * 4] = xn;
  }

  // ---- z1 to LDS: z[j= og*4+o][p][t]
#pragma unroll
  for (int o = 0; o < 4; ++o)
    *(float4*)&z1s[(og * 4 + o) * 128 + p * 32 + u * 4] =
        make_float4(a1[o][0], a1[o][1], a1[o][2], a1[o][3]);
  __syncthreads();

  // ---- stage 2: a2[oo][k] = sum_j qw2T[j][og*16+oo] * z[j][t], 16 o2/thread
  float a2[16][4];
#pragma unroll
  for (int oo = 0; oo < 16; ++oo)
#pragma unroll
    for (int k = 0; k < 4; ++k) a2[oo][k] = 0.f;

  const float* w2base = qw2T + og * 16;
#pragma unroll 4
  for (int j = 0; j < 32; ++j) {
    float4 zv = *(const float4*)&z1s[j * 128 + p * 32 + u * 4];
    float z[4] = {zv.x, zv.y, zv.z, zv.w};
    float4 wA = *(const float4*)(w2base + j * 128);
    float4 wB = *(const float4*)(w2base + j * 128 + 4);
    float4 wC = *(const float4*)(w2base + j * 128 + 8);
    float4 wD = *(const float4*)(w2base + j * 128 + 12);
    float w[16] = {wA.x, wA.y, wA.z, wA.w, wB.x, wB.y, wB.z, wB.w,
                   wC.x, wC.y, wC.z, wC.w, wD.x, wD.y, wD.z, wD.w};
#pragma unroll
    for (int oo = 0; oo < 16; ++oo)
#pragma unroll
      for (int k = 0; k < 4; ++k) a2[oo][k] += w[oo] * z[k];
  }

  // ---- epilogue: cumsum over t, subtract kappa, clip, diff, store
  float4 kA = *(const float4*)(kap + og * 16);
  float4 kB = *(const float4*)(kap + og * 16 + 4);
  float4 kC = *(const float4*)(kap + og * 16 + 8);
  float4 kD = *(const float4*)(kap + og * 16 + 12);
  float kv[16] = {kA.x, kA.y, kA.z, kA.w, kB.x, kB.y, kB.z, kB.w,
                  kC.x, kC.y, kC.z, kC.w, kD.x, kD.y, kD.z, kD.w};
  float* outb = out + (size_t)n * CIN * CHUNKF + coloff;

#pragma unroll
  for (int oo = 0; oo < 16; ++oo) {
    float c0 = a2[oo][0];
    float c1 = c0 + a2[oo][1];
    float c2 = c1 + a2[oo][2];
    float c3 = c2 + a2[oo][3];
    // inclusive 8-lane (u) prefix of quad totals
    float incl = c3;
    float t1 = __shfl_up(incl, 1); if (u >= 1) incl += t1;
    float t2 = __shfl_up(incl, 2); if (u >= 2) incl += t2;
    float t4 = __shfl_up(incl, 4); if (u >= 4) incl += t4;
    float base = (incl - c3) - kv[oo];        // S[4u-1] - kappa
    float prev = (u == 0) ? 0.f : fminf(fmaxf(base, -6.f), 6.f);
    float A0 = fminf(fmaxf(base + c0, -6.f), 6.f);
    float A1 = fminf(fmaxf(base + c1, -6.f), 6.f);
    float A2 = fminf(fmaxf(base + c2, -6.f), 6.f);
    float A3 = fminf(fmaxf(base + c3, -6.f), 6.f);
    float* op = outb + (size_t)(og * 16 + oo) * CHUNKF;
    *(float4*)op = make_float4(A0 - prev, A1 - A0, A2 - A1, A3 - A2);
  }
}

extern "C" void kernel_launch(void* const* d_in, const int* in_sizes, int n_in,
                              void* d_out, int out_size, void* d_ws, size_t ws_size,
                              hipStream_t stream) {
  const float* x  = (const float*)d_in[0];
  const float* v1 = (const float*)d_in[1];
  const float* g1 = (const float*)d_in[2];
  const float* v2 = (const float*)d_in[3];
  const float* g2 = (const float*)d_in[4];
  float* ws  = (float*)d_ws;
  float* out = (float*)d_out;

  hipMemsetAsync(ws + 8192, 0, 128 * sizeof(float), stream);
  wnorm_kernel<<<160, 128, 0, stream>>>(v1, g1, v2, g2, ws);
  mean_kernel<<<2048, 256, 0, stream>>>(x, ws + 8192);
  kappa_kernel<<<1, 128, 0, stream>>>(ws);
  fused_kernel<<<1024, 256, 0, stream>>>(x, ws, out);
}